// Round 16
// baseline (103.999 us; speedup 1.0000x reference)
//
#include <hip/hip_runtime.h>
#include <math.h>
#include <stdint.h>

#define N_RAYS    2048
#define N_SAMPLES 32
#define NPTS      (N_RAYS * N_SAMPLES)   // 65536
#define NV        6890
#define G         32
#define NCELLS    (G * G * G)            // 32768
#define SPLIT     8                      // lanes cooperating per point (grid path)
#define RMAX      3                      // cap on shell radius; beyond -> fallback brute force
#define QMASK     0xFFFFE000u            // keep exponent + 10 mantissa bits
#define IMASK     0x1FFFu                // 13-bit sorted-vertex index (NV < 8192)
#define CMASK     0x1FFFu                // 13-bit count in cellinfo

// near-tie flag margin: covers 2 quantization quanta (2^-10 rel each) + f32 error
#define TIE_REL   3e-3f
#define TIE_ABS   2e-5f

// ---- workspace layout (bytes) ----
#define WS_COUNT     0                                 // u32 tie count
#define WS_FBC       4                                 // u32 fallback count
#define WS_PARAMS    16                                // float[12]: org[3], h[3], inv_h[3]
#define WS_HIST      128                               // u32[NCELLS]; DEAD after build -> idx16
#define WS_ROWMASK   (WS_HIST + 4 * NCELLS)            // u32[G*G]
#define WS_CELLINFO  (WS_ROWMASK + 4 * G * G)          // u32[NCELLS] = start<<13|cnt
#define WS_SVERTS    (WS_CELLINFO + 4 * NCELLS)        // float4[NV], 16-aligned
#define WS_ORIGIDX   (WS_SVERTS + 16 * NV)             // u16[NV]
#define WS_LIST      (WS_ORIGIDX + 2 * NV + 12)        // u16[NPTS]
#define WS_NEEDED    (WS_LIST + 2 * NPTS)              // ~521 KB (unsorted tier)
#define WS_PHIST     (WS_NEEDED)                       // u32[NCELLS] point-cell hist/starts
#define WS_ORDER     (WS_PHIST + 4 * NCELLS)           // u16[NPTS] sorted point order
#define WS_NEEDED2   (WS_ORDER + 2 * NPTS)             // ~784 KB (sorted tier)
#define WS_IDX       WS_HIST                           // alias: idx16 u16[NPTS] over dead hist
#define WS_ZERO_W    ((WS_CELLINFO) / 4)               // zero words [0,4) and [32, this)

__device__ __forceinline__ uint64_t umin64(uint64_t a, uint64_t b) { return a < b ? a : b; }
__device__ __forceinline__ uint64_t umax64(uint64_t a, uint64_t b) { return a < b ? b : a; }

__device__ __forceinline__ int cell_clamp(float x, float org, float ih) {
    int c = (int)floorf((x - org) * ih);
    return min(max(c, 0), G - 1);
}

// ---- K0: fused zero + bounds. block 0: bbox->params; blocks 1..: zero hist(+phist) ----
__global__ __launch_bounds__(256) void init_kernel(const float* __restrict__ verts,
                                                   float* __restrict__ params,
                                                   uint32_t* __restrict__ wzero,
                                                   uint32_t* __restrict__ phist) {
    const int t = threadIdx.x;
    if (blockIdx.x != 0) {
        for (int i = (blockIdx.x - 1) * 256 + t; i < WS_ZERO_W; i += (gridDim.x - 1) * 256) {
            if (i >= 4 && i < 32) continue;   // skip params region
            wzero[i] = 0u;
        }
        if (phist) {
            for (int i = (blockIdx.x - 1) * 256 + t; i < NCELLS; i += (gridDim.x - 1) * 256)
                phist[i] = 0u;
        }
        return;
    }
    __shared__ float mn[3][256], mx[3][256];
    float lmn[3] = {1e30f, 1e30f, 1e30f}, lmx[3] = {-1e30f, -1e30f, -1e30f};
    for (int v = t; v < NV; v += 256) {
        #pragma unroll
        for (int d = 0; d < 3; ++d) {
            float x = verts[v * 3 + d];
            lmn[d] = fminf(lmn[d], x); lmx[d] = fmaxf(lmx[d], x);
        }
    }
    #pragma unroll
    for (int d = 0; d < 3; ++d) { mn[d][t] = lmn[d]; mx[d][t] = lmx[d]; }
    __syncthreads();
    for (int s = 128; s > 0; s >>= 1) {
        if (t < s) {
            #pragma unroll
            for (int d = 0; d < 3; ++d) {
                mn[d][t] = fminf(mn[d][t], mn[d][t + s]);
                mx[d][t] = fmaxf(mx[d][t], mx[d][t + s]);
            }
        }
        __syncthreads();
    }
    if (t == 0) {
        #pragma unroll
        for (int d = 0; d < 3; ++d) {
            const float lo = mn[d][0] - 1e-3f, hi = mx[d][0] + 1e-3f;
            const float span = fmaxf(hi - lo, 1e-2f);
            params[d]     = lo;
            params[3 + d] = span / (float)G;
            params[6 + d] = (float)G / span;
        }
    }
}

// ---- K1: fused histogram — verts (i<NV) + points (i<NPTS); 256 blocks x 256 ----
__global__ __launch_bounds__(256) void hist2_kernel(
    const float* __restrict__ verts, const float* __restrict__ pts,
    const float* __restrict__ params,
    uint32_t* __restrict__ hist, uint32_t* __restrict__ phist)
{
    const int i = blockIdx.x * blockDim.x + threadIdx.x;
    const float og0 = params[0], og1 = params[1], og2 = params[2];
    const float ih0 = params[6], ih1 = params[7], ih2 = params[8];
    if (i < NV) {
        const int cx = cell_clamp(verts[i * 3 + 0], og0, ih0);
        const int cy = cell_clamp(verts[i * 3 + 1], og1, ih1);
        const int cz = cell_clamp(verts[i * 3 + 2], og2, ih2);
        atomicAdd(&hist[(cz * G + cy) * G + cx], 1u);
    }
    if (i < NPTS) {
        const int cx = cell_clamp(pts[i * 3 + 0], og0, ih0);
        const int cy = cell_clamp(pts[i * 3 + 1], og1, ih1);
        const int cz = cell_clamp(pts[i * 3 + 2], og2, ih2);
        if (phist) atomicAdd(&phist[(cz * G + cy) * G + cx], 1u);
    }
}

// legacy single-hist (unsorted tier)
__global__ void hist_kernel(const float* __restrict__ verts, const float* __restrict__ params,
                            uint32_t* __restrict__ hist) {
    const int v = blockIdx.x * blockDim.x + threadIdx.x;
    if (v >= NV) return;
    const int cx = cell_clamp(verts[v * 3 + 0], params[0], params[6]);
    const int cy = cell_clamp(verts[v * 3 + 1], params[1], params[7]);
    const int cz = cell_clamp(verts[v * 3 + 2], params[2], params[8]);
    atomicAdd(&hist[(cz * G + cy) * G + cx], 1u);
}

// ---- K2: 1-block dual prefix scan, 2 barriers (shfl hierarchy) ----
// verts: hist -> cellinfo(start<<13|cnt) + rowmask (loc[] kept in regs).
// points: phist counts -> in-place exclusive starts (re-read to save regs).
__global__ __launch_bounds__(1024) void scan2_kernel(const uint32_t* __restrict__ hist,
                                                     uint32_t* __restrict__ cellinfo,
                                                     uint32_t* __restrict__ rowmask,
                                                     uint32_t* __restrict__ phist) {
    __shared__ uint32_t wsum[16], wsum2[16];
    const int t = threadIdx.x;
    const int lane = t & 63, wv = t >> 6;
    uint32_t loc[32];
    uint32_t sum = 0, rmask = 0, sum2 = 0;
    const int base = t * 32;
    #pragma unroll
    for (int i = 0; i < 32; ++i) {
        const uint32_t h = hist[base + i];
        loc[i] = sum; sum += h;
        if (h) rmask |= (1u << i);
    }
    rowmask[t] = rmask;
    if (phist) {
        #pragma unroll
        for (int i = 0; i < 32; ++i) sum2 += phist[base + i];
    }
    // inclusive scans of per-thread sums within the wave
    uint32_t inc = sum, inc2 = sum2;
    #pragma unroll
    for (int off = 1; off < 64; off <<= 1) {
        const uint32_t v = __shfl_up(inc, off);
        const uint32_t v2 = __shfl_up(inc2, off);
        if (lane >= off) { inc += v; inc2 += v2; }
    }
    if (lane == 63) { wsum[wv] = inc; wsum2[wv] = inc2; }
    __syncthreads();
    if (t < 16) {   // wave 0 scans the 16 wave totals (exclusive), both arrays
        const uint32_t v = wsum[t], v2 = wsum2[t];
        uint32_t p = v, p2 = v2;
        #pragma unroll
        for (int off = 1; off < 16; off <<= 1) {
            const uint32_t u = __shfl_up(p, off);
            const uint32_t u2 = __shfl_up(p2, off);
            if (t >= off) { p += u; p2 += u2; }
        }
        wsum[t] = p - v; wsum2[t] = p2 - v2;
    }
    __syncthreads();
    const uint32_t pre = wsum[wv] + (inc - sum);
    #pragma unroll
    for (int i = 0; i < 32; ++i) {
        const uint32_t nxt = (i == 31) ? sum : loc[i + 1];
        const uint32_t cnt = nxt - loc[i];
        cellinfo[base + i] = ((pre + loc[i]) << 13) | cnt;
    }
    if (phist) {
        uint32_t run = wsum2[wv] + (inc2 - sum2);
        #pragma unroll
        for (int i = 0; i < 32; ++i) {
            const uint32_t c = phist[base + i];
            phist[base + i] = run;       // in-place: count -> exclusive start
            run += c;
        }
    }
}

// legacy single-scan (unsorted tier)
__global__ __launch_bounds__(1024) void scan_cells_kernel(const uint32_t* __restrict__ hist,
                                                          uint32_t* __restrict__ cellinfo,
                                                          uint32_t* __restrict__ rowmask) {
    __shared__ uint32_t wsum[16];
    const int t = threadIdx.x;
    const int lane = t & 63, wv = t >> 6;
    uint32_t loc[32];
    uint32_t sum = 0, rmask = 0;
    const int base = t * 32;
    #pragma unroll
    for (int i = 0; i < 32; ++i) {
        const uint32_t h = hist[base + i];
        loc[i] = sum; sum += h;
        if (h) rmask |= (1u << i);
    }
    rowmask[t] = rmask;
    uint32_t inc = sum;
    #pragma unroll
    for (int off = 1; off < 64; off <<= 1) {
        const uint32_t v = __shfl_up(inc, off);
        if (lane >= off) inc += v;
    }
    if (lane == 63) wsum[wv] = inc;
    __syncthreads();
    if (t < 16) {
        const uint32_t v = wsum[t];
        uint32_t p = v;
        #pragma unroll
        for (int off = 1; off < 16; off <<= 1) {
            const uint32_t u = __shfl_up(p, off);
            if (t >= off) p += u;
        }
        wsum[t] = p - v;
    }
    __syncthreads();
    const uint32_t pre = wsum[wv] + (inc - sum);
    #pragma unroll
    for (int i = 0; i < 32; ++i) {
        const uint32_t nxt = (i == 31) ? sum : loc[i + 1];
        const uint32_t cnt = nxt - loc[i];
        cellinfo[base + i] = ((pre + loc[i]) << 13) | cnt;
    }
}

// ---- K3: fused scatter — verts into sverts, points into order16 ----
__global__ __launch_bounds__(256) void scatter2_kernel(
    const float* __restrict__ verts, const float* __restrict__ pts,
    const float* __restrict__ params,
    uint32_t* __restrict__ hist, const uint32_t* __restrict__ cellinfo,
    float4* __restrict__ sverts, uint16_t* __restrict__ origidx,
    uint32_t* __restrict__ phist, uint16_t* __restrict__ order16)
{
    const int i = blockIdx.x * blockDim.x + threadIdx.x;
    const float og0 = params[0], og1 = params[1], og2 = params[2];
    const float ih0 = params[6], ih1 = params[7], ih2 = params[8];
    if (i < NV) {
        const float x = verts[i * 3 + 0], y = verts[i * 3 + 1], z = verts[i * 3 + 2];
        const int cx = cell_clamp(x, og0, ih0);
        const int cy = cell_clamp(y, og1, ih1);
        const int cz = cell_clamp(z, og2, ih2);
        const int c = (cz * G + cy) * G + cx;
        const uint32_t old = atomicSub(&hist[c], 1u);
        const uint32_t pos = (cellinfo[c] >> 13) + old - 1u;
        sverts[pos] = make_float4(x, y, z, fmaf(x, x, fmaf(y, y, z * z)));
        origidx[pos] = (uint16_t)i;
    }
    if (i < NPTS && phist) {
        const int cx = cell_clamp(pts[i * 3 + 0], og0, ih0);
        const int cy = cell_clamp(pts[i * 3 + 1], og1, ih1);
        const int cz = cell_clamp(pts[i * 3 + 2], og2, ih2);
        const int c = (cz * G + cy) * G + cx;
        const uint32_t pos = atomicAdd(&phist[c], 1u);
        order16[pos] = (uint16_t)i;
    }
}

// legacy scatter (unsorted tier)
__global__ void scatter_kernel(const float* __restrict__ verts, const float* __restrict__ params,
                               uint32_t* __restrict__ hist, const uint32_t* __restrict__ cellinfo,
                               float4* __restrict__ sverts, uint16_t* __restrict__ origidx) {
    const int v = blockIdx.x * blockDim.x + threadIdx.x;
    if (v >= NV) return;
    const float x = verts[v * 3 + 0], y = verts[v * 3 + 1], z = verts[v * 3 + 2];
    const int cx = cell_clamp(x, params[0], params[6]);
    const int cy = cell_clamp(y, params[1], params[7]);
    const int cz = cell_clamp(z, params[2], params[8]);
    const int c = (cz * G + cy) * G + cx;
    const uint32_t old = atomicSub(&hist[c], 1u);
    const uint32_t pos = (cellinfo[c] >> 13) + old - 1u;
    sverts[pos] = make_float4(x, y, z, fmaf(x, x, fmaf(y, y, z * z)));
    origidx[pos] = (uint16_t)v;
}

// ---- K4: search — 3^3 box pass, then shells r=2..RMAX; points in sorted order ----
__global__ __launch_bounds__(256) void search_kernel(
    const float* __restrict__ pts, const float* __restrict__ params,
    const uint32_t* __restrict__ rowmask, const uint32_t* __restrict__ cellinfo,
    const float4* __restrict__ sverts, const uint16_t* __restrict__ origidx,
    const uint16_t* __restrict__ order16,
    uint16_t* __restrict__ idx16, uint16_t* __restrict__ list16,
    uint32_t* __restrict__ count, uint32_t* __restrict__ fbcount)
{
    __shared__ uint32_t srow[G * G];
    const int tid = threadIdx.x;
    for (int i = tid; i < G * G; i += 256) srow[i] = rowmask[i];
    __syncthreads();

    const int gtid = blockIdx.x * 256 + tid;
    const int sub  = gtid & (SPLIT - 1);
    const int q    = gtid / SPLIT;
    const int n    = order16 ? (int)order16[q] : q;
    const float px = pts[n * 3 + 0], py = pts[n * 3 + 1], pz = pts[n * 3 + 2];
    const float acc = -0.5f * fmaf(px, px, fmaf(py, py, pz * pz));
    const float org0 = params[0], org1 = params[1], org2 = params[2];
    const float h0 = params[3], h1 = params[4], h2 = params[5];
    const int cx = cell_clamp(px, org0, params[6]);
    const int cy = cell_clamp(py, org1, params[7]);
    const int cz = cell_clamp(pz, org2, params[8]);

    uint32_t k1 = ~0u, k2 = ~0u;   // per-lane LOCAL top-2 over DISJOINT vert sets
    bool unproven = true;

    auto scan_run = [&](int rowG, int a, int b) {
        const uint32_t i0 = cellinfo[rowG + a];
        const uint32_t i1 = cellinfo[rowG + b];
        const uint32_t s = i0 >> 13;
        const uint32_t e = (i1 >> 13) + (i1 & CMASK);
        for (uint32_t j = s + sub; j < e; j += SPLIT) {
            const float4 qv = sverts[j];
            const float dot = fmaf(px, qv.x, fmaf(py, qv.y, fmaf(pz, qv.z, acc)));
            const float d = fmaxf(fmaf(-2.f, dot, qv.w), 0.f);
            const uint32_t k = (__float_as_uint(d) & QMASK) | j;
            k2 = min(k2, max(k1, k)); k1 = min(k1, k);
        }
    };
    auto proven = [&](int xl, int xh, int yl, int yh, int zl, int zh) -> bool {
        uint32_t m1 = k1;
        #pragma unroll
        for (int off = 1; off < SPLIT; off <<= 1)
            m1 = min(m1, (uint32_t)__shfl_xor((int)m1, off));
        if (m1 == ~0u) return false;
        float dmin = 1e30f;
        bool any = false;
        if (xl > 0)     { dmin = fminf(dmin, px - fmaf((float)xl,      h0, org0)); any = true; }
        if (xh < G - 1) { dmin = fminf(dmin, fmaf((float)(xh + 1), h0, org0) - px); any = true; }
        if (yl > 0)     { dmin = fminf(dmin, py - fmaf((float)yl,      h1, org1)); any = true; }
        if (yh < G - 1) { dmin = fminf(dmin, fmaf((float)(yh + 1), h1, org1) - py); any = true; }
        if (zl > 0)     { dmin = fminf(dmin, pz - fmaf((float)zl,      h2, org2)); any = true; }
        if (zh < G - 1) { dmin = fminf(dmin, fmaf((float)(zh + 1), h2, org2) - pz); any = true; }
        if (!any) return true;                         // whole grid searched
        const float dout = fmaxf(dmin, 0.f);
        const float d1f = __uint_as_float(m1 & QMASK); // rounded-down d1: conservative
        return dout * dout > fmaf(d1f, 1.05f, 1e-3f);
    };

    // ---- pass 0: clamped 3^3 box (== shells r=0,1), one run per row ----
    const int xlo1 = max(cx - 1, 0), xhi1 = min(cx + 1, G - 1);
    const int ylo1 = max(cy - 1, 0), yhi1 = min(cy + 1, G - 1);
    const int zlo1 = max(cz - 1, 0), zhi1 = min(cz + 1, G - 1);
    {
        const uint32_t wm = (uint32_t)((((uint64_t)1 << (xhi1 - xlo1 + 1)) - 1) << xlo1);
        for (int z = zlo1; z <= zhi1; ++z)
            for (int y = ylo1; y <= yhi1; ++y) {
                const int row = z * G + y;
                if (srow[row] & wm) scan_run(row * G, xlo1, xhi1);
            }
    }
    if (proven(xlo1, xhi1, ylo1, yhi1, zlo1, zhi1)) unproven = false;

    // ---- shells r=2..RMAX with incremental stop tests ----
    if (unproven) {
        for (int r = 2; r <= RMAX; ++r) {
            const int xlo = max(cx - r, 0), xhi = min(cx + r, G - 1);
            const int ylo = max(cy - r, 0), yhi = min(cy + r, G - 1);
            const int zlo = max(cz - r, 0), zhi = min(cz + r, G - 1);
            const uint32_t wm = (uint32_t)((((uint64_t)1 << (xhi - xlo + 1)) - 1) << xlo);
            for (int z = zlo; z <= zhi; ++z) {
                const int az = abs(z - cz);
                for (int y = ylo; y <= yhi; ++y) {
                    const int row = z * G + y;
                    const int ayz = max(abs(y - cy), az);
                    if (ayz == r) {
                        if (srow[row] & wm) scan_run(row * G, xlo, xhi);
                    } else {
                        #pragma unroll
                        for (int side = 0; side < 2; ++side) {
                            const int x = side ? cx + r : cx - r;
                            if (x < 0 || x > G - 1) continue;
                            if (!((srow[row] >> x) & 1u)) continue;
                            scan_run(row * G, x, x);
                        }
                    }
                }
            }
            if (proven(xlo, xhi, ylo, yhi, zlo, zhi)) { unproven = false; break; }
        }
    }

    // single final clean merge of the disjoint per-lane locals
    #pragma unroll
    for (int off = 1; off < SPLIT; off <<= 1) {
        const uint32_t o1 = (uint32_t)__shfl_xor((int)k1, off);
        const uint32_t o2 = (uint32_t)__shfl_xor((int)k2, off);
        k2 = min(min(k2, o2), max(k1, o1)); k1 = min(k1, o1);
    }

    if (sub == 0) {
        if (unproven) {
            const uint32_t p = atomicAdd(fbcount, 1u);
            list16[NPTS - 1 - p] = (uint16_t)n;       // fallback list, top-down
        } else {
            const float d1 = __uint_as_float(k1 & QMASK);
            const float d2 = __uint_as_float(k2 & QMASK);
            idx16[n] = origidx[k1 & IMASK];
            if (d2 - d1 < fmaf(TIE_REL, d1, TIE_ABS)) {
                const uint32_t p = atomicAdd(count, 1u);
                list16[p] = (uint16_t)n;              // tie list, bottom-up
            }
        }
    }
}

// ---- K5: fused fixup — fallback brute force + tie refinement, one wave per point ----
__global__ __launch_bounds__(256) void fixup_kernel(
    const float* __restrict__ pts,
    const float4* __restrict__ sverts, const uint16_t* __restrict__ origidx,
    uint16_t* __restrict__ list16,
    const uint32_t* __restrict__ count, const uint32_t* __restrict__ fbcount,
    uint16_t* __restrict__ idx16)
{
    const uint32_t fcnt = *fbcount;
    const uint32_t tcnt = *count;
    const uint32_t total = fcnt + tcnt;
    const int wv = threadIdx.x >> 6, lane = threadIdx.x & 63;
    for (uint32_t jj = blockIdx.x * 4 + wv; jj < total; jj += gridDim.x * 4) {
        const bool isFb = jj < fcnt;
        const int n = isFb ? (int)list16[NPTS - 1 - jj] : (int)list16[jj - fcnt];
        const float px = pts[n * 3 + 0], py = pts[n * 3 + 1], pz = pts[n * 3 + 2];
        bool needF64 = true;
        if (isFb) {
            const float acc = -0.5f * fmaf(px, px, fmaf(py, py, pz * pz));
            uint32_t k1 = ~0u, k2 = ~0u;
            int v = lane;
            for (; v + 192 < NV; v += 256) {
                const float4 q0 = sverts[v];
                const float4 q1 = sverts[v + 64];
                const float4 q2 = sverts[v + 128];
                const float4 q3 = sverts[v + 192];
                float dot, d; uint32_t k;
                dot = fmaf(px, q0.x, fmaf(py, q0.y, fmaf(pz, q0.z, acc)));
                d = fmaxf(fmaf(-2.f, dot, q0.w), 0.f);
                k = (__float_as_uint(d) & QMASK) | (uint32_t)v;
                k2 = min(k2, max(k1, k)); k1 = min(k1, k);
                dot = fmaf(px, q1.x, fmaf(py, q1.y, fmaf(pz, q1.z, acc)));
                d = fmaxf(fmaf(-2.f, dot, q1.w), 0.f);
                k = (__float_as_uint(d) & QMASK) | (uint32_t)(v + 64);
                k2 = min(k2, max(k1, k)); k1 = min(k1, k);
                dot = fmaf(px, q2.x, fmaf(py, q2.y, fmaf(pz, q2.z, acc)));
                d = fmaxf(fmaf(-2.f, dot, q2.w), 0.f);
                k = (__float_as_uint(d) & QMASK) | (uint32_t)(v + 128);
                k2 = min(k2, max(k1, k)); k1 = min(k1, k);
                dot = fmaf(px, q3.x, fmaf(py, q3.y, fmaf(pz, q3.z, acc)));
                d = fmaxf(fmaf(-2.f, dot, q3.w), 0.f);
                k = (__float_as_uint(d) & QMASK) | (uint32_t)(v + 192);
                k2 = min(k2, max(k1, k)); k1 = min(k1, k);
            }
            for (; v < NV; v += 64) {
                const float4 q = sverts[v];
                const float dot = fmaf(px, q.x, fmaf(py, q.y, fmaf(pz, q.z, acc)));
                const float d = fmaxf(fmaf(-2.f, dot, q.w), 0.f);
                const uint32_t k = (__float_as_uint(d) & QMASK) | (uint32_t)v;
                k2 = min(k2, max(k1, k)); k1 = min(k1, k);
            }
            #pragma unroll
            for (int off = 1; off < 64; off <<= 1) {
                const uint32_t o1 = (uint32_t)__shfl_xor((int)k1, off);
                const uint32_t o2 = (uint32_t)__shfl_xor((int)k2, off);
                k2 = min(min(k2, o2), max(k1, o1)); k1 = min(k1, o1);
            }
            const float d1 = __uint_as_float(k1 & QMASK);
            const float d2 = __uint_as_float(k2 & QMASK);
            needF64 = (d2 - d1 < fmaf(TIE_REL, d1, TIE_ABS));
            if (!needF64 && lane == 0) idx16[n] = origidx[k1 & IMASK];
        }
        if (needF64) {
            const double pxd = (double)px, pyd = (double)py, pzd = (double)pz;
            double best = 1e300; uint32_t bi = 0xFFFFFFFFu;
            int v = lane;
            for (; v + 192 < NV; v += 256) {
                const float4 q0 = sverts[v];
                const float4 q1 = sverts[v + 64];
                const float4 q2 = sverts[v + 128];
                const float4 q3 = sverts[v + 192];
                const uint32_t o0 = origidx[v];
                const uint32_t o1 = origidx[v + 64];
                const uint32_t o2 = origidx[v + 128];
                const uint32_t o3 = origidx[v + 192];
                double dx, dy, dz, d;
                dx = pxd - (double)q0.x; dy = pyd - (double)q0.y; dz = pzd - (double)q0.z;
                d = dx*dx + dy*dy + dz*dz;
                if (d < best || (d == best && o0 < bi)) { best = d; bi = o0; }
                dx = pxd - (double)q1.x; dy = pyd - (double)q1.y; dz = pzd - (double)q1.z;
                d = dx*dx + dy*dy + dz*dz;
                if (d < best || (d == best && o1 < bi)) { best = d; bi = o1; }
                dx = pxd - (double)q2.x; dy = pyd - (double)q2.y; dz = pzd - (double)q2.z;
                d = dx*dx + dy*dy + dz*dz;
                if (d < best || (d == best && o2 < bi)) { best = d; bi = o2; }
                dx = pxd - (double)q3.x; dy = pyd - (double)q3.y; dz = pzd - (double)q3.z;
                d = dx*dx + dy*dy + dz*dz;
                if (d < best || (d == best && o3 < bi)) { best = d; bi = o3; }
            }
            for (; v < NV; v += 64) {
                const float4 q = sverts[v];
                const uint32_t oi = origidx[v];
                const double dx = pxd - (double)q.x;
                const double dy = pyd - (double)q.y;
                const double dz = pzd - (double)q.z;
                const double d = dx*dx + dy*dy + dz*dz;
                if (d < best || (d == best && oi < bi)) { best = d; bi = oi; }
            }
            #pragma unroll
            for (int off = 1; off < 64; off <<= 1) {
                const double od = __shfl_xor(best, off);
                const uint32_t oi = (uint32_t)__shfl_xor((int)bi, off);
                if (od < best || (od == best && oi < bi)) { best = od; bi = oi; }
            }
            if (lane == 0) idx16[n] = (uint16_t)bi;
        }
    }
}

// ---- K6: gather T (float4), f64 cofactor inverse, transform, finite-diff dirs ----
__global__ __launch_bounds__(256) void output_kernel(
    const float* __restrict__ pts, const float* __restrict__ Ts,
    const uint16_t* __restrict__ idx16, float* __restrict__ out)
{
    __shared__ double sc[256][3];
    const int tid = threadIdx.x;
    const int n = blockIdx.x * 256 + tid;    // block = 8 whole rays
    const float px = pts[n*3+0], py = pts[n*3+1], pz = pts[n*3+2];
    const int v = (int)idx16[n];

    const float4* T4 = reinterpret_cast<const float4*>(Ts + (size_t)v * 16);
    const float4 r0 = T4[0], r1 = T4[1], r2 = T4[2], r3 = T4[3];
    const double m[16] = { r0.x, r0.y, r0.z, r0.w,  r1.x, r1.y, r1.z, r1.w,
                           r2.x, r2.y, r2.z, r2.w,  r3.x, r3.y, r3.z, r3.w };
    double inv[16];
    inv[0]  =  m[5]*m[10]*m[15] - m[5]*m[11]*m[14] - m[9]*m[6]*m[15] + m[9]*m[7]*m[14] + m[13]*m[6]*m[11] - m[13]*m[7]*m[10];
    inv[4]  = -m[4]*m[10]*m[15] + m[4]*m[11]*m[14] + m[8]*m[6]*m[15] - m[8]*m[7]*m[14] - m[12]*m[6]*m[11] + m[12]*m[7]*m[10];
    inv[8]  =  m[4]*m[9]*m[15] - m[4]*m[11]*m[13] - m[8]*m[5]*m[15] + m[8]*m[7]*m[13] + m[12]*m[5]*m[11] - m[12]*m[7]*m[9];
    inv[12] = -m[4]*m[9]*m[14] + m[4]*m[10]*m[13] + m[8]*m[5]*m[14] - m[8]*m[6]*m[13] - m[12]*m[5]*m[10] + m[12]*m[6]*m[9];
    inv[1]  = -m[1]*m[10]*m[15] + m[1]*m[11]*m[14] + m[9]*m[2]*m[15] - m[9]*m[3]*m[14] - m[13]*m[2]*m[11] + m[13]*m[3]*m[10];
    inv[5]  =  m[0]*m[10]*m[15] - m[0]*m[11]*m[14] - m[8]*m[2]*m[15] + m[8]*m[3]*m[14] + m[12]*m[2]*m[11] - m[12]*m[3]*m[10];
    inv[9]  = -m[0]*m[9]*m[15] + m[0]*m[11]*m[13] + m[8]*m[1]*m[15] - m[8]*m[3]*m[13] - m[12]*m[1]*m[11] + m[12]*m[3]*m[9];
    inv[13] =  m[0]*m[9]*m[14] - m[0]*m[10]*m[13] - m[8]*m[1]*m[14] + m[8]*m[2]*m[13] + m[12]*m[1]*m[10] - m[12]*m[2]*m[9];
    inv[2]  =  m[1]*m[6]*m[15] - m[1]*m[7]*m[14] - m[5]*m[2]*m[15] + m[5]*m[3]*m[14] + m[13]*m[2]*m[7] - m[13]*m[3]*m[6];
    inv[6]  = -m[0]*m[6]*m[15] + m[0]*m[7]*m[14] + m[4]*m[2]*m[15] - m[4]*m[3]*m[14] - m[12]*m[2]*m[7] + m[12]*m[3]*m[6];
    inv[10] =  m[0]*m[5]*m[15] - m[0]*m[7]*m[13] - m[4]*m[1]*m[15] + m[4]*m[3]*m[13] + m[12]*m[1]*m[7] - m[12]*m[3]*m[5];
    inv[14] = -m[0]*m[5]*m[14] + m[0]*m[6]*m[13] + m[4]*m[1]*m[14] - m[4]*m[2]*m[13] - m[12]*m[1]*m[6] + m[12]*m[2]*m[5];
    inv[3]  = -m[1]*m[6]*m[11] + m[1]*m[7]*m[10] + m[5]*m[2]*m[11] - m[5]*m[3]*m[10] - m[9]*m[2]*m[7] + m[9]*m[3]*m[6];
    inv[7]  =  m[0]*m[6]*m[11] - m[0]*m[7]*m[10] - m[4]*m[2]*m[11] + m[4]*m[3]*m[10] + m[8]*m[2]*m[7] - m[8]*m[3]*m[6];
    inv[11] = -m[0]*m[5]*m[11] + m[0]*m[7]*m[9] + m[4]*m[1]*m[11] - m[4]*m[3]*m[9] - m[8]*m[1]*m[7] + m[8]*m[3]*m[5];
    inv[15] =  m[0]*m[5]*m[10] - m[0]*m[6]*m[9] - m[4]*m[1]*m[10] + m[4]*m[2]*m[9] + m[8]*m[1]*m[6] - m[8]*m[2]*m[5];
    const double det = m[0]*inv[0] + m[1]*inv[4] + m[2]*inv[8] + m[3]*inv[12];
    const double rd = 1.0 / det;

    const double hx = -(double)px, hy = -(double)py, hz = (double)pz;
    const double c0 = (inv[0]*hx + inv[1]*hy + inv[2]*hz  + inv[3])  * rd;
    const double c1 = (inv[4]*hx + inv[5]*hy + inv[6]*hz  + inv[7])  * rd;
    const double c2 = (inv[8]*hx + inv[9]*hy + inv[10]*hz + inv[11]) * rd;
    const double f0 = -c0, f1 = -c1, f2 = c2;   // can * [-1,-1,1]

    out[n*3+0] = (float)f0; out[n*3+1] = (float)f1; out[n*3+2] = (float)f2;
    sc[tid][0] = f0; sc[tid][1] = f1; sc[tid][2] = f2;
    __syncthreads();

    int l0 = tid, l1 = tid + 1;
    if ((tid & (N_SAMPLES - 1)) == N_SAMPLES - 1) { l0 = tid - 1; l1 = tid; }
    const double dx = sc[l1][0] - sc[l0][0];
    const double dy = sc[l1][1] - sc[l0][1];
    const double dz = sc[l1][2] - sc[l0][2];
    const double nr = fmax(sqrt(dx*dx + dy*dy + dz*dz), 1e-12);
    float* o = out + (size_t)NPTS * 3 + (size_t)n * 3;
    o[0] = (float)(dx / nr); o[1] = (float)(dy / nr); o[2] = (float)(dz / nr);
}

// ---- brute-force path (used only if ws too small) ----
__global__ void zero_kernel(uint32_t* __restrict__ w, int nwords) {
    for (int i = blockIdx.x * blockDim.x + threadIdx.x; i < nwords; i += gridDim.x * blockDim.x)
        w[i] = 0u;
}

__global__ __launch_bounds__(256) void scan_kernel(
    const float* __restrict__ pts, const float* __restrict__ verts,
    uint16_t* __restrict__ idx16, uint16_t* __restrict__ list16,
    uint32_t* __restrict__ count)
{
    __shared__ float4 sv[2048];
    const int tid  = threadIdx.x;
    const int part = tid & 7;
    const int grp  = tid >> 3;
    const int n0   = blockIdx.x * 64 + grp * 2;
    const float ax = pts[n0*3+0], ay = pts[n0*3+1], az = pts[n0*3+2];
    const float bx = pts[n0*3+3], by = pts[n0*3+4], bz = pts[n0*3+5];
    const float acc = -0.5f * fmaf(ax, ax, fmaf(ay, ay, az*az));
    const float bcc = -0.5f * fmaf(bx, bx, fmaf(by, by, bz*bz));
    uint64_t ak1 = ~0ull, ak2 = ~0ull, bk1 = ~0ull, bk2 = ~0ull;
    for (int base = 0; base < NV; base += 2048) {
        const int cnt = min(NV - base, 2048);
        __syncthreads();
        for (int v = tid; v < cnt; v += 256) {
            const float x = verts[(base+v)*3+0], y = verts[(base+v)*3+1], z = verts[(base+v)*3+2];
            sv[v] = make_float4(x, y, z, fmaf(x, x, fmaf(y, y, z*z)));
        }
        __syncthreads();
        #pragma unroll 4
        for (int v = part; v < cnt; v += 8) {
            const float4 q = sv[v];
            const uint64_t vi = (uint64_t)(base + v);
            float s, d; uint64_t k;
            s = fmaf(ax, q.x, fmaf(ay, q.y, fmaf(az, q.z, acc)));
            d = fmaxf(fmaf(-2.f, s, q.w), 0.f);
            k = ((uint64_t)__float_as_uint(d) << 32) | vi;
            ak2 = umin64(ak2, umax64(ak1, k)); ak1 = umin64(ak1, k);
            s = fmaf(bx, q.x, fmaf(by, q.y, fmaf(bz, q.z, bcc)));
            d = fmaxf(fmaf(-2.f, s, q.w), 0.f);
            k = ((uint64_t)__float_as_uint(d) << 32) | vi;
            bk2 = umin64(bk2, umax64(bk1, k)); bk1 = umin64(bk1, k);
        }
    }
    #pragma unroll
    for (int off = 1; off < 8; off <<= 1) {
        uint64_t o1, o2;
        o1 = __shfl_xor((unsigned long long)ak1, off); o2 = __shfl_xor((unsigned long long)ak2, off);
        ak2 = umin64(umin64(ak2, o2), umax64(ak1, o1)); ak1 = umin64(ak1, o1);
        o1 = __shfl_xor((unsigned long long)bk1, off); o2 = __shfl_xor((unsigned long long)bk2, off);
        bk2 = umin64(umin64(bk2, o2), umax64(bk1, o1)); bk1 = umin64(bk1, o1);
    }
    if (part == 0) {
        const float ad1 = __uint_as_float((uint32_t)(ak1 >> 32));
        const float ad2 = __uint_as_float((uint32_t)(ak2 >> 32));
        idx16[n0] = (uint16_t)(ak1 & 0xFFFFu);
        if (ad2 - ad1 < fmaf(1e-4f, ad1, TIE_ABS)) { uint32_t p = atomicAdd(count, 1u); list16[p] = (uint16_t)n0; }
        const float bd1 = __uint_as_float((uint32_t)(bk1 >> 32));
        const float bd2 = __uint_as_float((uint32_t)(bk2 >> 32));
        idx16[n0+1] = (uint16_t)(bk1 & 0xFFFFu);
        if (bd2 - bd1 < fmaf(1e-4f, bd1, TIE_ABS)) { uint32_t p = atomicAdd(count, 1u); list16[p] = (uint16_t)(n0+1); }
    }
}

__global__ __launch_bounds__(256) void refine_kernel(
    const float* __restrict__ pts, const float* __restrict__ verts,
    const uint16_t* __restrict__ list16, const uint32_t* __restrict__ count,
    uint16_t* __restrict__ idx16)
{
    const uint32_t cnt = *count;
    const int wv = threadIdx.x >> 6, lane = threadIdx.x & 63;
    for (uint32_t j = blockIdx.x * 4 + wv; j < cnt; j += gridDim.x * 4) {
        const int n = (int)list16[j];
        const double px = (double)pts[n*3+0];
        const double py = (double)pts[n*3+1];
        const double pz = (double)pts[n*3+2];
        double best = 1e300; uint32_t bi = 0xFFFFFFFFu;
        for (int v = lane; v < NV; v += 64) {
            const double dx = px - (double)verts[v*3+0];
            const double dy = py - (double)verts[v*3+1];
            const double dz = pz - (double)verts[v*3+2];
            const double d = dx*dx + dy*dy + dz*dz;
            if (d < best || (d == best && (uint32_t)v < bi)) { best = d; bi = (uint32_t)v; }
        }
        #pragma unroll
        for (int off = 1; off < 64; off <<= 1) {
            const double od = __shfl_xor(best, off);
            const uint32_t oi = (uint32_t)__shfl_xor((int)bi, off);
            if (od < best || (od == best && oi < bi)) { best = od; bi = oi; }
        }
        if (lane == 0) idx16[n] = (uint16_t)bi;
    }
}

// ---- launch ----------------------------------------------------------------
extern "C" void kernel_launch(void* const* d_in, const int* in_sizes, int n_in,
                              void* d_out, int out_size, void* d_ws, size_t ws_size,
                              hipStream_t stream) {
    const float* pts   = (const float*)d_in[0];   // rays_points_world
    const float* verts = (const float*)d_in[2];   // vertices_posed
    const float* Ts    = (const float*)d_in[3];   // Ts
    float* out = (float*)d_out;

    uint8_t* ws = (uint8_t*)d_ws;
    uint32_t* count   = (uint32_t*)(ws + WS_COUNT);
    uint32_t* fbcount = (uint32_t*)(ws + WS_FBC);

    if (ws_size >= (size_t)WS_NEEDED) {
        float*    params   = (float*)(ws + WS_PARAMS);
        uint32_t* hist     = (uint32_t*)(ws + WS_HIST);
        uint32_t* rowmask  = (uint32_t*)(ws + WS_ROWMASK);
        uint32_t* cellinfo = (uint32_t*)(ws + WS_CELLINFO);
        float4*   sverts   = (float4*)(ws + WS_SVERTS);
        uint16_t* origidx  = (uint16_t*)(ws + WS_ORIGIDX);
        uint16_t* idx16    = (uint16_t*)(ws + WS_IDX);   // aliases dead hist
        uint16_t* list16   = (uint16_t*)(ws + WS_LIST);
        const bool sorted  = ws_size >= (size_t)WS_NEEDED2;
        uint32_t* phist    = sorted ? (uint32_t*)(ws + WS_PHIST) : nullptr;
        uint16_t* order16  = sorted ? (uint16_t*)(ws + WS_ORDER) : nullptr;
        const int vblocks = (NV + 255) / 256;

        hipLaunchKernelGGL(init_kernel, dim3(65), dim3(256), 0, stream,
                           verts, params, (uint32_t*)ws, phist);
        if (sorted) {
            hipLaunchKernelGGL(hist2_kernel, dim3(NPTS / 256), dim3(256), 0, stream,
                               verts, pts, params, hist, phist);
            hipLaunchKernelGGL(scan2_kernel, dim3(1), dim3(1024), 0, stream,
                               hist, cellinfo, rowmask, phist);
            hipLaunchKernelGGL(scatter2_kernel, dim3(NPTS / 256), dim3(256), 0, stream,
                               verts, pts, params, hist, cellinfo, sverts, origidx,
                               phist, order16);
        } else {
            hipLaunchKernelGGL(hist_kernel, dim3(vblocks), dim3(256), 0, stream,
                               verts, params, hist);
            hipLaunchKernelGGL(scan_cells_kernel, dim3(1), dim3(1024), 0, stream,
                               hist, cellinfo, rowmask);
            hipLaunchKernelGGL(scatter_kernel, dim3(vblocks), dim3(256), 0, stream,
                               verts, params, hist, cellinfo, sverts, origidx);
        }
        hipLaunchKernelGGL(search_kernel, dim3(NPTS * SPLIT / 256), dim3(256), 0, stream,
                           pts, params, rowmask, cellinfo, sverts, origidx, order16,
                           idx16, list16, count, fbcount);
        hipLaunchKernelGGL(fixup_kernel, dim3(1024), dim3(256), 0, stream,
                           pts, sverts, origidx, list16, count, fbcount, idx16);
        hipLaunchKernelGGL(output_kernel, dim3(NPTS / 256), dim3(256), 0, stream,
                           pts, Ts, idx16, out);
    } else {
        // fallback: brute force (needs only count + idx16 + list16)
        uint16_t* idx16  = (uint16_t*)(ws + 64);
        uint16_t* list16 = (uint16_t*)(ws + 64 + 2 * NPTS);
        hipLaunchKernelGGL(zero_kernel, dim3(1), dim3(64), 0, stream, (uint32_t*)ws, 1);
        hipLaunchKernelGGL(scan_kernel, dim3(NPTS / 64), dim3(256), 0, stream,
                           pts, verts, idx16, list16, count);
        hipLaunchKernelGGL(refine_kernel, dim3(512), dim3(256), 0, stream,
                           pts, verts, list16, count, idx16);
        hipLaunchKernelGGL(output_kernel, dim3(NPTS / 256), dim3(256), 0, stream,
                           pts, Ts, idx16, out);
    }
}

// Round 17
// 81.736 us; speedup vs baseline: 1.2724x; 1.2724x over previous
//
#include <hip/hip_runtime.h>
#include <math.h>
#include <stdint.h>

#define N_RAYS    2048
#define N_SAMPLES 32
#define NPTS      (N_RAYS * N_SAMPLES)   // 65536
#define NV        6890
#define G         32
#define NCELLS    (G * G * G)            // 32768
#define SPLIT     8                      // lanes cooperating per point (grid path)
#define RMAX      3                      // cap on shell radius; beyond -> fallback brute force
#define QMASK     0xFFFFE000u            // keep exponent + 10 mantissa bits
#define IMASK     0x1FFFu                // 13-bit sorted-vertex index (NV < 8192)
#define CMASK     0x1FFFu                // 13-bit count in cellinfo

// near-tie flag margin: covers 2 quantization quanta (2^-10 rel each) + f32 error
#define TIE_REL   3e-3f
#define TIE_ABS   2e-5f

// ---- workspace layout (bytes) ----
#define WS_COUNT     0                                 // u32 tie count
#define WS_FBC       4                                 // u32 fallback count
#define WS_PARAMS    16                                // float[12]: org[3], h[3], inv_h[3]
#define WS_HIST      128                               // u32[NCELLS]; DEAD after build -> idx16
#define WS_ROWMASK   (WS_HIST + 4 * NCELLS)            // u32[G*G]
#define WS_CELLINFO  (WS_ROWMASK + 4 * G * G)          // u32[NCELLS] = start<<13|cnt
#define WS_SVERTS    (WS_CELLINFO + 4 * NCELLS)        // float4[NV], 16-aligned
#define WS_ORIGIDX   (WS_SVERTS + 16 * NV)             // u16[NV]
#define WS_LIST      (WS_ORIGIDX + 2 * NV + 12)        // u16[NPTS]: ties bottom-up, fallback top-down
#define WS_NEEDED    (WS_LIST + 2 * NPTS)              // ~521 KB
#define WS_IDX       WS_HIST                           // alias: idx16 u16[NPTS] over dead hist
#define WS_ZERO_W    ((WS_CELLINFO) / 4)               // zero words [0,4) and [32, this)

__device__ __forceinline__ uint64_t umin64(uint64_t a, uint64_t b) { return a < b ? a : b; }
__device__ __forceinline__ uint64_t umax64(uint64_t a, uint64_t b) { return a < b ? b : a; }

__device__ __forceinline__ int cell_clamp(float x, float org, float ih) {
    int c = (int)floorf((x - org) * ih);
    return min(max(c, 0), G - 1);
}

// ---- K0: fused zero + bounds. block 0: bbox->params; blocks 1..: zero counters/hist ----
__global__ __launch_bounds__(256) void init_kernel(const float* __restrict__ verts,
                                                   float* __restrict__ params,
                                                   uint32_t* __restrict__ wzero) {
    const int t = threadIdx.x;
    if (blockIdx.x != 0) {
        for (int i = (blockIdx.x - 1) * 256 + t; i < WS_ZERO_W; i += (gridDim.x - 1) * 256) {
            if (i >= 4 && i < 32) continue;   // skip params region
            wzero[i] = 0u;
        }
        return;
    }
    __shared__ float mn[3][256], mx[3][256];
    float lmn[3] = {1e30f, 1e30f, 1e30f}, lmx[3] = {-1e30f, -1e30f, -1e30f};
    for (int v = t; v < NV; v += 256) {
        #pragma unroll
        for (int d = 0; d < 3; ++d) {
            float x = verts[v * 3 + d];
            lmn[d] = fminf(lmn[d], x); lmx[d] = fmaxf(lmx[d], x);
        }
    }
    #pragma unroll
    for (int d = 0; d < 3; ++d) { mn[d][t] = lmn[d]; mx[d][t] = lmx[d]; }
    __syncthreads();
    for (int s = 128; s > 0; s >>= 1) {
        if (t < s) {
            #pragma unroll
            for (int d = 0; d < 3; ++d) {
                mn[d][t] = fminf(mn[d][t], mn[d][t + s]);
                mx[d][t] = fmaxf(mx[d][t], mx[d][t + s]);
            }
        }
        __syncthreads();
    }
    if (t == 0) {
        #pragma unroll
        for (int d = 0; d < 3; ++d) {
            const float lo = mn[d][0] - 1e-3f, hi = mx[d][0] + 1e-3f;
            const float span = fmaxf(hi - lo, 1e-2f);
            params[d]     = lo;
            params[3 + d] = span / (float)G;
            params[6 + d] = (float)G / span;
        }
    }
}

// ---- K1: histogram ----
__global__ void hist_kernel(const float* __restrict__ verts, const float* __restrict__ params,
                            uint32_t* __restrict__ hist) {
    const int v = blockIdx.x * blockDim.x + threadIdx.x;
    if (v >= NV) return;
    const int cx = cell_clamp(verts[v * 3 + 0], params[0], params[6]);
    const int cy = cell_clamp(verts[v * 3 + 1], params[1], params[7]);
    const int cz = cell_clamp(verts[v * 3 + 2], params[2], params[8]);
    atomicAdd(&hist[(cz * G + cy) * G + cx], 1u);
}

// ---- K2: 1-block prefix scan, 2 barriers total (shfl hierarchy) ----
__global__ __launch_bounds__(1024) void scan_cells_kernel(const uint32_t* __restrict__ hist,
                                                          uint32_t* __restrict__ cellinfo,
                                                          uint32_t* __restrict__ rowmask) {
    __shared__ uint32_t wsum[16];
    const int t = threadIdx.x;
    const int lane = t & 63, wv = t >> 6;
    uint32_t loc[32];
    uint32_t sum = 0, rmask = 0;
    const int base = t * 32;
    #pragma unroll
    for (int i = 0; i < 32; ++i) {
        const uint32_t h = hist[base + i];
        loc[i] = sum; sum += h;
        if (h) rmask |= (1u << i);
    }
    rowmask[t] = rmask;
    uint32_t inc = sum;
    #pragma unroll
    for (int off = 1; off < 64; off <<= 1) {
        const uint32_t v = __shfl_up(inc, off);
        if (lane >= off) inc += v;
    }
    if (lane == 63) wsum[wv] = inc;
    __syncthreads();
    if (t < 16) {
        const uint32_t v = wsum[t];
        uint32_t p = v;
        #pragma unroll
        for (int off = 1; off < 16; off <<= 1) {
            const uint32_t u = __shfl_up(p, off);
            if (t >= off) p += u;
        }
        wsum[t] = p - v;
    }
    __syncthreads();
    const uint32_t pre = wsum[wv] + (inc - sum);   // exclusive prefix for thread t
    #pragma unroll
    for (int i = 0; i < 32; ++i) {
        const uint32_t nxt = (i == 31) ? sum : loc[i + 1];
        const uint32_t cnt = nxt - loc[i];
        cellinfo[base + i] = ((pre + loc[i]) << 13) | cnt;   // start<8192, cnt<8192
    }
}

// ---- K3: scatter vertices into sorted order (multi-block; hist holds counts) ----
__global__ void scatter_kernel(const float* __restrict__ verts, const float* __restrict__ params,
                               uint32_t* __restrict__ hist, const uint32_t* __restrict__ cellinfo,
                               float4* __restrict__ sverts, uint16_t* __restrict__ origidx) {
    const int v = blockIdx.x * blockDim.x + threadIdx.x;
    if (v >= NV) return;
    const float x = verts[v * 3 + 0], y = verts[v * 3 + 1], z = verts[v * 3 + 2];
    const int cx = cell_clamp(x, params[0], params[6]);
    const int cy = cell_clamp(y, params[1], params[7]);
    const int cz = cell_clamp(z, params[2], params[8]);
    const int c = (cz * G + cy) * G + cx;
    const uint32_t old = atomicSub(&hist[c], 1u);
    const uint32_t pos = (cellinfo[c] >> 13) + old - 1u;
    sverts[pos] = make_float4(x, y, z, fmaf(x, x, fmaf(y, y, z * z)));
    origidx[pos] = (uint16_t)v;
}

// ---- K4: search — 3^3 box pass, then shells r=2..RMAX ----
__global__ __launch_bounds__(256) void search_kernel(
    const float* __restrict__ pts, const float* __restrict__ params,
    const uint32_t* __restrict__ rowmask, const uint32_t* __restrict__ cellinfo,
    const float4* __restrict__ sverts, const uint16_t* __restrict__ origidx,
    uint16_t* __restrict__ idx16, uint16_t* __restrict__ list16,
    uint32_t* __restrict__ count, uint32_t* __restrict__ fbcount)
{
    __shared__ uint32_t srow[G * G];
    const int tid = threadIdx.x;
    for (int i = tid; i < G * G; i += 256) srow[i] = rowmask[i];
    __syncthreads();

    const int gtid = blockIdx.x * 256 + tid;
    const int sub  = gtid & (SPLIT - 1);
    const int n    = gtid / SPLIT;
    const float px = pts[n * 3 + 0], py = pts[n * 3 + 1], pz = pts[n * 3 + 2];
    const float acc = -0.5f * fmaf(px, px, fmaf(py, py, pz * pz));
    const float org0 = params[0], org1 = params[1], org2 = params[2];
    const float h0 = params[3], h1 = params[4], h2 = params[5];
    const int cx = cell_clamp(px, org0, params[6]);
    const int cy = cell_clamp(py, org1, params[7]);
    const int cz = cell_clamp(pz, org2, params[8]);

    uint32_t k1 = ~0u, k2 = ~0u;   // per-lane LOCAL top-2 over DISJOINT vert sets
    bool unproven = true;

    auto scan_run = [&](int rowG, int a, int b) {
        const uint32_t i0 = cellinfo[rowG + a];
        const uint32_t i1 = cellinfo[rowG + b];
        const uint32_t s = i0 >> 13;
        const uint32_t e = (i1 >> 13) + (i1 & CMASK);
        for (uint32_t j = s + sub; j < e; j += SPLIT) {
            const float4 q = sverts[j];
            const float dot = fmaf(px, q.x, fmaf(py, q.y, fmaf(pz, q.z, acc)));
            const float d = fmaxf(fmaf(-2.f, dot, q.w), 0.f);
            const uint32_t k = (__float_as_uint(d) & QMASK) | j;
            k2 = min(k2, max(k1, k)); k1 = min(k1, k);
        }
    };
    auto proven = [&](int xl, int xh, int yl, int yh, int zl, int zh) -> bool {
        uint32_t m1 = k1;
        #pragma unroll
        for (int off = 1; off < SPLIT; off <<= 1)
            m1 = min(m1, (uint32_t)__shfl_xor((int)m1, off));
        if (m1 == ~0u) return false;
        float dmin = 1e30f;
        bool any = false;
        if (xl > 0)     { dmin = fminf(dmin, px - fmaf((float)xl,      h0, org0)); any = true; }
        if (xh < G - 1) { dmin = fminf(dmin, fmaf((float)(xh + 1), h0, org0) - px); any = true; }
        if (yl > 0)     { dmin = fminf(dmin, py - fmaf((float)yl,      h1, org1)); any = true; }
        if (yh < G - 1) { dmin = fminf(dmin, fmaf((float)(yh + 1), h1, org1) - py); any = true; }
        if (zl > 0)     { dmin = fminf(dmin, pz - fmaf((float)zl,      h2, org2)); any = true; }
        if (zh < G - 1) { dmin = fminf(dmin, fmaf((float)(zh + 1), h2, org2) - pz); any = true; }
        if (!any) return true;                         // whole grid searched
        const float dout = fmaxf(dmin, 0.f);
        const float d1f = __uint_as_float(m1 & QMASK); // rounded-down d1: conservative
        return dout * dout > fmaf(d1f, 1.05f, 1e-3f);
    };

    // ---- pass 0: clamped 3^3 box (== shells r=0,1), one run per row ----
    const int xlo1 = max(cx - 1, 0), xhi1 = min(cx + 1, G - 1);
    const int ylo1 = max(cy - 1, 0), yhi1 = min(cy + 1, G - 1);
    const int zlo1 = max(cz - 1, 0), zhi1 = min(cz + 1, G - 1);
    {
        const uint32_t wm = (uint32_t)((((uint64_t)1 << (xhi1 - xlo1 + 1)) - 1) << xlo1);
        for (int z = zlo1; z <= zhi1; ++z)
            for (int y = ylo1; y <= yhi1; ++y) {
                const int row = z * G + y;
                if (srow[row] & wm) scan_run(row * G, xlo1, xhi1);
            }
    }
    if (proven(xlo1, xhi1, ylo1, yhi1, zlo1, zhi1)) unproven = false;

    // ---- shells r=2..RMAX with incremental stop tests ----
    if (unproven) {
        for (int r = 2; r <= RMAX; ++r) {
            const int xlo = max(cx - r, 0), xhi = min(cx + r, G - 1);
            const int ylo = max(cy - r, 0), yhi = min(cy + r, G - 1);
            const int zlo = max(cz - r, 0), zhi = min(cz + r, G - 1);
            const uint32_t wm = (uint32_t)((((uint64_t)1 << (xhi - xlo + 1)) - 1) << xlo);
            for (int z = zlo; z <= zhi; ++z) {
                const int az = abs(z - cz);
                for (int y = ylo; y <= yhi; ++y) {
                    const int row = z * G + y;
                    const int ayz = max(abs(y - cy), az);
                    if (ayz == r) {
                        if (srow[row] & wm) scan_run(row * G, xlo, xhi);
                    } else {
                        #pragma unroll
                        for (int side = 0; side < 2; ++side) {
                            const int x = side ? cx + r : cx - r;
                            if (x < 0 || x > G - 1) continue;
                            if (!((srow[row] >> x) & 1u)) continue;
                            scan_run(row * G, x, x);
                        }
                    }
                }
            }
            if (proven(xlo, xhi, ylo, yhi, zlo, zhi)) { unproven = false; break; }
        }
    }

    // single final clean merge of the disjoint per-lane locals
    #pragma unroll
    for (int off = 1; off < SPLIT; off <<= 1) {
        const uint32_t o1 = (uint32_t)__shfl_xor((int)k1, off);
        const uint32_t o2 = (uint32_t)__shfl_xor((int)k2, off);
        k2 = min(min(k2, o2), max(k1, o1)); k1 = min(k1, o1);
    }

    if (sub == 0) {
        if (unproven) {
            const uint32_t p = atomicAdd(fbcount, 1u);
            list16[NPTS - 1 - p] = (uint16_t)n;       // fallback list, top-down
        } else {
            const float d1 = __uint_as_float(k1 & QMASK);
            const float d2 = __uint_as_float(k2 & QMASK);
            idx16[n] = origidx[k1 & IMASK];
            if (d2 - d1 < fmaf(TIE_REL, d1, TIE_ABS)) {
                const uint32_t p = atomicAdd(count, 1u);
                list16[p] = (uint16_t)n;              // tie list, bottom-up
            }
        }
    }
}

// ---- K5: fused fixup — fallback brute force + tie refinement, one wave per point ----
__global__ __launch_bounds__(256) void fixup_kernel(
    const float* __restrict__ pts,
    const float4* __restrict__ sverts, const uint16_t* __restrict__ origidx,
    uint16_t* __restrict__ list16,
    const uint32_t* __restrict__ count, const uint32_t* __restrict__ fbcount,
    uint16_t* __restrict__ idx16)
{
    const uint32_t fcnt = *fbcount;
    const uint32_t tcnt = *count;
    const uint32_t total = fcnt + tcnt;
    const int wv = threadIdx.x >> 6, lane = threadIdx.x & 63;
    for (uint32_t jj = blockIdx.x * 4 + wv; jj < total; jj += gridDim.x * 4) {
        const bool isFb = jj < fcnt;
        const int n = isFb ? (int)list16[NPTS - 1 - jj] : (int)list16[jj - fcnt];
        const float px = pts[n * 3 + 0], py = pts[n * 3 + 1], pz = pts[n * 3 + 2];
        bool needF64 = true;
        if (isFb) {
            const float acc = -0.5f * fmaf(px, px, fmaf(py, py, pz * pz));
            uint32_t k1 = ~0u, k2 = ~0u;
            int v = lane;
            for (; v + 192 < NV; v += 256) {
                const float4 q0 = sverts[v];
                const float4 q1 = sverts[v + 64];
                const float4 q2 = sverts[v + 128];
                const float4 q3 = sverts[v + 192];
                float dot, d; uint32_t k;
                dot = fmaf(px, q0.x, fmaf(py, q0.y, fmaf(pz, q0.z, acc)));
                d = fmaxf(fmaf(-2.f, dot, q0.w), 0.f);
                k = (__float_as_uint(d) & QMASK) | (uint32_t)v;
                k2 = min(k2, max(k1, k)); k1 = min(k1, k);
                dot = fmaf(px, q1.x, fmaf(py, q1.y, fmaf(pz, q1.z, acc)));
                d = fmaxf(fmaf(-2.f, dot, q1.w), 0.f);
                k = (__float_as_uint(d) & QMASK) | (uint32_t)(v + 64);
                k2 = min(k2, max(k1, k)); k1 = min(k1, k);
                dot = fmaf(px, q2.x, fmaf(py, q2.y, fmaf(pz, q2.z, acc)));
                d = fmaxf(fmaf(-2.f, dot, q2.w), 0.f);
                k = (__float_as_uint(d) & QMASK) | (uint32_t)(v + 128);
                k2 = min(k2, max(k1, k)); k1 = min(k1, k);
                dot = fmaf(px, q3.x, fmaf(py, q3.y, fmaf(pz, q3.z, acc)));
                d = fmaxf(fmaf(-2.f, dot, q3.w), 0.f);
                k = (__float_as_uint(d) & QMASK) | (uint32_t)(v + 192);
                k2 = min(k2, max(k1, k)); k1 = min(k1, k);
            }
            for (; v < NV; v += 64) {
                const float4 q = sverts[v];
                const float dot = fmaf(px, q.x, fmaf(py, q.y, fmaf(pz, q.z, acc)));
                const float d = fmaxf(fmaf(-2.f, dot, q.w), 0.f);
                const uint32_t k = (__float_as_uint(d) & QMASK) | (uint32_t)v;
                k2 = min(k2, max(k1, k)); k1 = min(k1, k);
            }
            #pragma unroll
            for (int off = 1; off < 64; off <<= 1) {
                const uint32_t o1 = (uint32_t)__shfl_xor((int)k1, off);
                const uint32_t o2 = (uint32_t)__shfl_xor((int)k2, off);
                k2 = min(min(k2, o2), max(k1, o1)); k1 = min(k1, o1);
            }
            const float d1 = __uint_as_float(k1 & QMASK);
            const float d2 = __uint_as_float(k2 & QMASK);
            needF64 = (d2 - d1 < fmaf(TIE_REL, d1, TIE_ABS));
            if (!needF64 && lane == 0) idx16[n] = origidx[k1 & IMASK];
        }
        if (needF64) {
            const double pxd = (double)px, pyd = (double)py, pzd = (double)pz;
            double best = 1e300; uint32_t bi = 0xFFFFFFFFu;
            int v = lane;
            for (; v + 192 < NV; v += 256) {
                const float4 q0 = sverts[v];
                const float4 q1 = sverts[v + 64];
                const float4 q2 = sverts[v + 128];
                const float4 q3 = sverts[v + 192];
                const uint32_t o0 = origidx[v];
                const uint32_t o1 = origidx[v + 64];
                const uint32_t o2 = origidx[v + 128];
                const uint32_t o3 = origidx[v + 192];
                double dx, dy, dz, d;
                dx = pxd - (double)q0.x; dy = pyd - (double)q0.y; dz = pzd - (double)q0.z;
                d = dx*dx + dy*dy + dz*dz;
                if (d < best || (d == best && o0 < bi)) { best = d; bi = o0; }
                dx = pxd - (double)q1.x; dy = pyd - (double)q1.y; dz = pzd - (double)q1.z;
                d = dx*dx + dy*dy + dz*dz;
                if (d < best || (d == best && o1 < bi)) { best = d; bi = o1; }
                dx = pxd - (double)q2.x; dy = pyd - (double)q2.y; dz = pzd - (double)q2.z;
                d = dx*dx + dy*dy + dz*dz;
                if (d < best || (d == best && o2 < bi)) { best = d; bi = o2; }
                dx = pxd - (double)q3.x; dy = pyd - (double)q3.y; dz = pzd - (double)q3.z;
                d = dx*dx + dy*dy + dz*dz;
                if (d < best || (d == best && o3 < bi)) { best = d; bi = o3; }
            }
            for (; v < NV; v += 64) {
                const float4 q = sverts[v];
                const uint32_t oi = origidx[v];
                const double dx = pxd - (double)q.x;
                const double dy = pyd - (double)q.y;
                const double dz = pzd - (double)q.z;
                const double d = dx*dx + dy*dy + dz*dz;
                if (d < best || (d == best && oi < bi)) { best = d; bi = oi; }
            }
            #pragma unroll
            for (int off = 1; off < 64; off <<= 1) {
                const double od = __shfl_xor(best, off);
                const uint32_t oi = (uint32_t)__shfl_xor((int)bi, off);
                if (od < best || (od == best && oi < bi)) { best = od; bi = oi; }
            }
            if (lane == 0) idx16[n] = (uint16_t)bi;
        }
    }
}

// ---- K6: gather T (float4), f64 cofactor inverse, transform, finite-diff dirs ----
__global__ __launch_bounds__(256) void output_kernel(
    const float* __restrict__ pts, const float* __restrict__ Ts,
    const uint16_t* __restrict__ idx16, float* __restrict__ out)
{
    __shared__ double sc[256][3];
    const int tid = threadIdx.x;
    const int n = blockIdx.x * 256 + tid;    // block = 8 whole rays
    const float px = pts[n*3+0], py = pts[n*3+1], pz = pts[n*3+2];
    const int v = (int)idx16[n];

    const float4* T4 = reinterpret_cast<const float4*>(Ts + (size_t)v * 16);
    const float4 r0 = T4[0], r1 = T4[1], r2 = T4[2], r3 = T4[3];
    const double m[16] = { r0.x, r0.y, r0.z, r0.w,  r1.x, r1.y, r1.z, r1.w,
                           r2.x, r2.y, r2.z, r2.w,  r3.x, r3.y, r3.z, r3.w };
    double inv[16];
    inv[0]  =  m[5]*m[10]*m[15] - m[5]*m[11]*m[14] - m[9]*m[6]*m[15] + m[9]*m[7]*m[14] + m[13]*m[6]*m[11] - m[13]*m[7]*m[10];
    inv[4]  = -m[4]*m[10]*m[15] + m[4]*m[11]*m[14] + m[8]*m[6]*m[15] - m[8]*m[7]*m[14] - m[12]*m[6]*m[11] + m[12]*m[7]*m[10];
    inv[8]  =  m[4]*m[9]*m[15] - m[4]*m[11]*m[13] - m[8]*m[5]*m[15] + m[8]*m[7]*m[13] + m[12]*m[5]*m[11] - m[12]*m[7]*m[9];
    inv[12] = -m[4]*m[9]*m[14] + m[4]*m[10]*m[13] + m[8]*m[5]*m[14] - m[8]*m[6]*m[13] - m[12]*m[5]*m[10] + m[12]*m[6]*m[9];
    inv[1]  = -m[1]*m[10]*m[15] + m[1]*m[11]*m[14] + m[9]*m[2]*m[15] - m[9]*m[3]*m[14] - m[13]*m[2]*m[11] + m[13]*m[3]*m[10];
    inv[5]  =  m[0]*m[10]*m[15] - m[0]*m[11]*m[14] - m[8]*m[2]*m[15] + m[8]*m[3]*m[14] + m[12]*m[2]*m[11] - m[12]*m[3]*m[10];
    inv[9]  = -m[0]*m[9]*m[15] + m[0]*m[11]*m[13] + m[8]*m[1]*m[15] - m[8]*m[3]*m[13] - m[12]*m[1]*m[11] + m[12]*m[3]*m[9];
    inv[13] =  m[0]*m[9]*m[14] - m[0]*m[10]*m[13] - m[8]*m[1]*m[14] + m[8]*m[2]*m[13] + m[12]*m[1]*m[10] - m[12]*m[2]*m[9];
    inv[2]  =  m[1]*m[6]*m[15] - m[1]*m[7]*m[14] - m[5]*m[2]*m[15] + m[5]*m[3]*m[14] + m[13]*m[2]*m[7] - m[13]*m[3]*m[6];
    inv[6]  = -m[0]*m[6]*m[15] + m[0]*m[7]*m[14] + m[4]*m[2]*m[15] - m[4]*m[3]*m[14] - m[12]*m[2]*m[7] + m[12]*m[3]*m[6];
    inv[10] =  m[0]*m[5]*m[15] - m[0]*m[7]*m[13] - m[4]*m[1]*m[15] + m[4]*m[3]*m[13] + m[12]*m[1]*m[7] - m[12]*m[3]*m[5];
    inv[14] = -m[0]*m[5]*m[14] + m[0]*m[6]*m[13] + m[4]*m[1]*m[14] - m[4]*m[2]*m[13] - m[12]*m[1]*m[6] + m[12]*m[2]*m[5];
    inv[3]  = -m[1]*m[6]*m[11] + m[1]*m[7]*m[10] + m[5]*m[2]*m[11] - m[5]*m[3]*m[10] - m[9]*m[2]*m[7] + m[9]*m[3]*m[6];
    inv[7]  =  m[0]*m[6]*m[11] - m[0]*m[7]*m[10] - m[4]*m[2]*m[11] + m[4]*m[3]*m[10] + m[8]*m[2]*m[7] - m[8]*m[3]*m[6];
    inv[11] = -m[0]*m[5]*m[11] + m[0]*m[7]*m[9] + m[4]*m[1]*m[11] - m[4]*m[3]*m[9] - m[8]*m[1]*m[7] + m[8]*m[3]*m[5];
    inv[15] =  m[0]*m[5]*m[10] - m[0]*m[6]*m[9] - m[4]*m[1]*m[10] + m[4]*m[2]*m[9] + m[8]*m[1]*m[6] - m[8]*m[2]*m[5];
    const double det = m[0]*inv[0] + m[1]*inv[4] + m[2]*inv[8] + m[3]*inv[12];
    const double rd = 1.0 / det;

    const double hx = -(double)px, hy = -(double)py, hz = (double)pz;
    const double c0 = (inv[0]*hx + inv[1]*hy + inv[2]*hz  + inv[3])  * rd;
    const double c1 = (inv[4]*hx + inv[5]*hy + inv[6]*hz  + inv[7])  * rd;
    const double c2 = (inv[8]*hx + inv[9]*hy + inv[10]*hz + inv[11]) * rd;
    const double f0 = -c0, f1 = -c1, f2 = c2;   // can * [-1,-1,1]

    out[n*3+0] = (float)f0; out[n*3+1] = (float)f1; out[n*3+2] = (float)f2;
    sc[tid][0] = f0; sc[tid][1] = f1; sc[tid][2] = f2;
    __syncthreads();

    int l0 = tid, l1 = tid + 1;
    if ((tid & (N_SAMPLES - 1)) == N_SAMPLES - 1) { l0 = tid - 1; l1 = tid; }
    const double dx = sc[l1][0] - sc[l0][0];
    const double dy = sc[l1][1] - sc[l0][1];
    const double dz = sc[l1][2] - sc[l0][2];
    const double nr = fmax(sqrt(dx*dx + dy*dy + dz*dz), 1e-12);
    float* o = out + (size_t)NPTS * 3 + (size_t)n * 3;
    o[0] = (float)(dx / nr); o[1] = (float)(dy / nr); o[2] = (float)(dz / nr);
}

// ---- brute-force path (used only if ws too small) ----
__global__ void zero_kernel(uint32_t* __restrict__ w, int nwords) {
    for (int i = blockIdx.x * blockDim.x + threadIdx.x; i < nwords; i += gridDim.x * blockDim.x)
        w[i] = 0u;
}

__global__ __launch_bounds__(256) void scan_kernel(
    const float* __restrict__ pts, const float* __restrict__ verts,
    uint16_t* __restrict__ idx16, uint16_t* __restrict__ list16,
    uint32_t* __restrict__ count)
{
    __shared__ float4 sv[2048];
    const int tid  = threadIdx.x;
    const int part = tid & 7;
    const int grp  = tid >> 3;
    const int n0   = blockIdx.x * 64 + grp * 2;
    const float ax = pts[n0*3+0], ay = pts[n0*3+1], az = pts[n0*3+2];
    const float bx = pts[n0*3+3], by = pts[n0*3+4], bz = pts[n0*3+5];
    const float acc = -0.5f * fmaf(ax, ax, fmaf(ay, ay, az*az));
    const float bcc = -0.5f * fmaf(bx, bx, fmaf(by, by, bz*bz));
    uint64_t ak1 = ~0ull, ak2 = ~0ull, bk1 = ~0ull, bk2 = ~0ull;
    for (int base = 0; base < NV; base += 2048) {
        const int cnt = min(NV - base, 2048);
        __syncthreads();
        for (int v = tid; v < cnt; v += 256) {
            const float x = verts[(base+v)*3+0], y = verts[(base+v)*3+1], z = verts[(base+v)*3+2];
            sv[v] = make_float4(x, y, z, fmaf(x, x, fmaf(y, y, z*z)));
        }
        __syncthreads();
        #pragma unroll 4
        for (int v = part; v < cnt; v += 8) {
            const float4 q = sv[v];
            const uint64_t vi = (uint64_t)(base + v);
            float s, d; uint64_t k;
            s = fmaf(ax, q.x, fmaf(ay, q.y, fmaf(az, q.z, acc)));
            d = fmaxf(fmaf(-2.f, s, q.w), 0.f);
            k = ((uint64_t)__float_as_uint(d) << 32) | vi;
            ak2 = umin64(ak2, umax64(ak1, k)); ak1 = umin64(ak1, k);
            s = fmaf(bx, q.x, fmaf(by, q.y, fmaf(bz, q.z, bcc)));
            d = fmaxf(fmaf(-2.f, s, q.w), 0.f);
            k = ((uint64_t)__float_as_uint(d) << 32) | vi;
            bk2 = umin64(bk2, umax64(bk1, k)); bk1 = umin64(bk1, k);
        }
    }
    #pragma unroll
    for (int off = 1; off < 8; off <<= 1) {
        uint64_t o1, o2;
        o1 = __shfl_xor((unsigned long long)ak1, off); o2 = __shfl_xor((unsigned long long)ak2, off);
        ak2 = umin64(umin64(ak2, o2), umax64(ak1, o1)); ak1 = umin64(ak1, o1);
        o1 = __shfl_xor((unsigned long long)bk1, off); o2 = __shfl_xor((unsigned long long)bk2, off);
        bk2 = umin64(umin64(bk2, o2), umax64(bk1, o1)); bk1 = umin64(bk1, o1);
    }
    if (part == 0) {
        const float ad1 = __uint_as_float((uint32_t)(ak1 >> 32));
        const float ad2 = __uint_as_float((uint32_t)(ak2 >> 32));
        idx16[n0] = (uint16_t)(ak1 & 0xFFFFu);
        if (ad2 - ad1 < fmaf(1e-4f, ad1, TIE_ABS)) { uint32_t p = atomicAdd(count, 1u); list16[p] = (uint16_t)n0; }
        const float bd1 = __uint_as_float((uint32_t)(bk1 >> 32));
        const float bd2 = __uint_as_float((uint32_t)(bk2 >> 32));
        idx16[n0+1] = (uint16_t)(bk1 & 0xFFFFu);
        if (bd2 - bd1 < fmaf(1e-4f, bd1, TIE_ABS)) { uint32_t p = atomicAdd(count, 1u); list16[p] = (uint16_t)(n0+1); }
    }
}

__global__ __launch_bounds__(256) void refine_kernel(
    const float* __restrict__ pts, const float* __restrict__ verts,
    const uint16_t* __restrict__ list16, const uint32_t* __restrict__ count,
    uint16_t* __restrict__ idx16)
{
    const uint32_t cnt = *count;
    const int wv = threadIdx.x >> 6, lane = threadIdx.x & 63;
    for (uint32_t j = blockIdx.x * 4 + wv; j < cnt; j += gridDim.x * 4) {
        const int n = (int)list16[j];
        const double px = (double)pts[n*3+0];
        const double py = (double)pts[n*3+1];
        const double pz = (double)pts[n*3+2];
        double best = 1e300; uint32_t bi = 0xFFFFFFFFu;
        for (int v = lane; v < NV; v += 64) {
            const double dx = px - (double)verts[v*3+0];
            const double dy = py - (double)verts[v*3+1];
            const double dz = pz - (double)verts[v*3+2];
            const double d = dx*dx + dy*dy + dz*dz;
            if (d < best || (d == best && (uint32_t)v < bi)) { best = d; bi = (uint32_t)v; }
        }
        #pragma unroll
        for (int off = 1; off < 64; off <<= 1) {
            const double od = __shfl_xor(best, off);
            const uint32_t oi = (uint32_t)__shfl_xor((int)bi, off);
            if (od < best || (od == best && oi < bi)) { best = od; bi = oi; }
        }
        if (lane == 0) idx16[n] = (uint16_t)bi;
    }
}

// ---- launch ----------------------------------------------------------------
extern "C" void kernel_launch(void* const* d_in, const int* in_sizes, int n_in,
                              void* d_out, int out_size, void* d_ws, size_t ws_size,
                              hipStream_t stream) {
    const float* pts   = (const float*)d_in[0];   // rays_points_world
    const float* verts = (const float*)d_in[2];   // vertices_posed
    const float* Ts    = (const float*)d_in[3];   // Ts
    float* out = (float*)d_out;

    uint8_t* ws = (uint8_t*)d_ws;
    uint32_t* count   = (uint32_t*)(ws + WS_COUNT);
    uint32_t* fbcount = (uint32_t*)(ws + WS_FBC);

    if (ws_size >= (size_t)WS_NEEDED) {
        float*    params   = (float*)(ws + WS_PARAMS);
        uint32_t* hist     = (uint32_t*)(ws + WS_HIST);
        uint32_t* rowmask  = (uint32_t*)(ws + WS_ROWMASK);
        uint32_t* cellinfo = (uint32_t*)(ws + WS_CELLINFO);
        float4*   sverts   = (float4*)(ws + WS_SVERTS);
        uint16_t* origidx  = (uint16_t*)(ws + WS_ORIGIDX);
        uint16_t* idx16    = (uint16_t*)(ws + WS_IDX);   // aliases dead hist
        uint16_t* list16   = (uint16_t*)(ws + WS_LIST);
        const int vblocks = (NV + 255) / 256;

        hipLaunchKernelGGL(init_kernel, dim3(65), dim3(256), 0, stream,
                           verts, params, (uint32_t*)ws);
        hipLaunchKernelGGL(hist_kernel, dim3(vblocks), dim3(256), 0, stream,
                           verts, params, hist);
        hipLaunchKernelGGL(scan_cells_kernel, dim3(1), dim3(1024), 0, stream,
                           hist, cellinfo, rowmask);
        hipLaunchKernelGGL(scatter_kernel, dim3(vblocks), dim3(256), 0, stream,
                           verts, params, hist, cellinfo, sverts, origidx);
        hipLaunchKernelGGL(search_kernel, dim3(NPTS * SPLIT / 256), dim3(256), 0, stream,
                           pts, params, rowmask, cellinfo, sverts, origidx,
                           idx16, list16, count, fbcount);
        hipLaunchKernelGGL(fixup_kernel, dim3(1024), dim3(256), 0, stream,
                           pts, sverts, origidx, list16, count, fbcount, idx16);
        hipLaunchKernelGGL(output_kernel, dim3(NPTS / 256), dim3(256), 0, stream,
                           pts, Ts, idx16, out);
    } else {
        // fallback: brute force (needs only count + idx16 + list16)
        uint16_t* idx16  = (uint16_t*)(ws + 64);
        uint16_t* list16 = (uint16_t*)(ws + 64 + 2 * NPTS);
        hipLaunchKernelGGL(zero_kernel, dim3(1), dim3(64), 0, stream, (uint32_t*)ws, 1);
        hipLaunchKernelGGL(scan_kernel, dim3(NPTS / 64), dim3(256), 0, stream,
                           pts, verts, idx16, list16, count);
        hipLaunchKernelGGL(refine_kernel, dim3(512), dim3(256), 0, stream,
                           pts, verts, list16, count, idx16);
        hipLaunchKernelGGL(output_kernel, dim3(NPTS / 256), dim3(256), 0, stream,
                           pts, Ts, idx16, out);
    }
}